// Round 10
// baseline (194.395 us; speedup 1.0000x reference)
//
#include <hip/hip_runtime.h>
#include <hip/hip_fp16.h>
#include <math.h>

#define BB 4
#define VV 256
#define HH 128
#define EPS 1e-5f

typedef __attribute__((ext_vector_type(8))) short short8;
typedef __attribute__((ext_vector_type(8))) __bf16 bf16x8;
typedef __attribute__((ext_vector_type(4))) float f32x4;

__device__ __forceinline__ float sigm_(float x) {
    float ex = __builtin_amdgcn_exp2f(-1.44269504f * x);
    return __builtin_amdgcn_rcpf(1.0f + ex);
}

__device__ __forceinline__ bf16x8 as_bf(short8 s) {
    union { short8 s; bf16x8 b; } u; u.s = s; return u.b;
}

// split via native converts (RNE); lo = RNE of residual
__device__ __forceinline__ void split8n(const float4 x0, const float4 x1,
                                        bf16x8& hi, bf16x8& lo) {
    float xs[8] = {x0.x, x0.y, x0.z, x0.w, x1.x, x1.y, x1.z, x1.w};
    #pragma unroll
    for (int i = 0; i < 8; ++i) {
        float x = xs[i];
        __bf16 h = (__bf16)x;
        float r = x - (float)h;
        hi[i] = h;
        lo[i] = (__bf16)r;
    }
}

// ---------------------------------------------------------------------------
// K0: split W_C into fragment-major bf16 hi/lo planes, PERMUTED mapping:
// fragment ns, lane l15 holds W_C row n_phys = l15*8 + ns.
// short8 idx = (kstep*8+nsub)*128 + plane*64 + lane
// k = kstep*32 + ((lane>>4)&3)*8 + i
// ---------------------------------------------------------------------------
__global__ __launch_bounds__(256) void k0_splitW(const float* __restrict__ W_C,
                                                 short* __restrict__ Whl) {
    int t = blockIdx.x * 256 + threadIdx.x;   // 0..2047
    int lane = t & 63;
    int grp = t >> 6;                         // kstep*8 + nsub
    int kstep = grp >> 3, nsub = grp & 7;
    int n = (lane & 15) * 8 + nsub;           // PERMUTED channel mapping
    int kb = kstep * 32 + ((lane >> 4) & 3) * 8;
    const float4* src = (const float4*)(W_C + (size_t)n * HH + kb);
    float4 x0 = src[0], x1 = src[1];
    bf16x8 hi, lo;
    split8n(x0, x1, hi, lo);
    union { bf16x8 b; short8 s; } uh, ul;
    uh.b = hi; ul.b = lo;
    short8* dst = (short8*)Whl;
    dst[(size_t)grp * 128 + 0 * 64 + lane] = uh.s;
    dst[(size_t)grp * 128 + 1 * 64 + lane] = ul.s;
}

// ---------------------------------------------------------------------------
// K1: six small linears, 4 rows/block (grid 256). Outputs normal layout
// and/or fragment-major PERMUTED: channel h of row R stored at
// (R*16 + (h>>3))*8 + (h&7).
// ---------------------------------------------------------------------------
struct LinArgs {
    const float* x1; const float* x2;
    const float* W[6]; const float* b[6]; const float* b2[6];
    float* out[6]; float* outf[6];
};

__global__ __launch_bounds__(128) void k1_linears(LinArgs a) {
    __shared__ float xs[2][4][HH];
    const int t = threadIdx.x;
    const int r0 = blockIdx.x * 4;
    {
        const float4* s1 = (const float4*)(a.x1 + (size_t)r0 * HH);
        const float4* s2 = (const float4*)(a.x2 + (size_t)r0 * HH);
        ((float4*)&xs[0][0][0])[t] = s1[t];
        ((float4*)&xs[1][0][0])[t] = s2[t];
    }
    __syncthreads();
    const int h = t;
    const int l15h = h >> 3, nsh = h & 7;     // PERMUTED fragment position
    for (int g = 0; g < 6; ++g) {
        const float* W = a.W[g];
        const float (*x)[HH] = (g < 3) ? xs[0] : xs[1];
        float acc[4];
        #pragma unroll
        for (int r = 0; r < 4; ++r) acc[r] = 0.f;
        const float4* Wrow = (const float4*)(W + (size_t)h * HH);
        #pragma unroll 8
        for (int kq = 0; kq < 32; ++kq) {
            float4 w4 = Wrow[kq];
            #pragma unroll
            for (int r = 0; r < 4; ++r) {
                float4 ev = *(const float4*)&x[r][kq * 4];
                acc[r] = fmaf(ev.x, w4.x, acc[r]);
                acc[r] = fmaf(ev.y, w4.y, acc[r]);
                acc[r] = fmaf(ev.z, w4.z, acc[r]);
                acc[r] = fmaf(ev.w, w4.w, acc[r]);
            }
        }
        float bias = a.b[g][h];
        if (a.b2[g]) bias += a.b2[g][h];
        if (a.out[g]) {
            float* O = a.out[g] + (size_t)r0 * HH + h;
            #pragma unroll
            for (int r = 0; r < 4; ++r) O[(size_t)r * HH] = acc[r] + bias;
        }
        if (a.outf[g]) {
            float* Of = a.outf[g];
            #pragma unroll
            for (int r = 0; r < 4; ++r)
                Of[((size_t)(r0 + r) * 16 + l15h) * 8 + nsh] = acc[r] + bias;
        }
    }
}

// ---------------------------------------------------------------------------
// K2: per (b,i,jhalf): e_new = e@W_C^T + A1f + A2f; packed-fp16/f32 store;
// h1 partial agg (atomic) + e BN stats. 512 thr = 8 waves, wave w covers
// j in [jhalf*128 + w*16, +16), n full 128. acc = 32 AGPR -> ~32 VGPR
// headroom for load hoisting. Full W (64 KB) in LDS.
// ---------------------------------------------------------------------------
template<int STOREH>
__global__ __launch_bounds__(512, 4) void k2_main(
    const float* __restrict__ e,
    const short* __restrict__ Whl,
    const float* __restrict__ A1f, const float* __restrict__ A2f,
    const float* __restrict__ V1f, const float* __restrict__ V2f,
    float* __restrict__ e_new32,
    unsigned short* __restrict__ e_newh,
    float* __restrict__ h1acc,
    float* __restrict__ stats)
{
    __shared__ short8 sW[4096];          // 64 KB: full W hi/lo
    __shared__ float red[8][3][8][16];   // 12 KB [wave][qty][ns][l15]
    const int t = threadIdx.x;
    const int l = t & 63;
    const int w = t >> 6;
    const int l15 = l & 15;
    const int lq = (l >> 4) & 3;
    const int blk = blockIdx.x;
    const int bi = blk >> 1;             // b*V + i
    const int jhalf = blk & 1;
    const int b = bi >> 8;
    const int jbase = jhalf * 128 + w * 16;

    {
        const short8* src = (const short8*)Whl;
        #pragma unroll
        for (int p = 0; p < 8; ++p) sW[p * 512 + t] = src[p * 512 + t];
    }
    __syncthreads();

    const float* pa = e + (size_t)bi * (VV * HH) +
                      (size_t)(jbase + l15) * HH + lq * 8;

    f32x4 acc[8];
    #pragma unroll
    for (int ns = 0; ns < 8; ++ns) acc[ns] = (f32x4){0.f, 0.f, 0.f, 0.f};

    float4 ec0 = *(const float4*)(pa);
    float4 ec1 = *(const float4*)(pa + 4);

    #pragma unroll
    for (int kstep = 0; kstep < 4; ++kstep) {
        bf16x8 ah, al;
        split8n(ec0, ec1, ah, al);
        if (kstep < 3) {
            const float* pn = pa + (kstep + 1) * 32;
            ec0 = *(const float4*)(pn);
            ec1 = *(const float4*)(pn + 4);
        }
        #pragma unroll
        for (int ns = 0; ns < 8; ++ns) {
            short8 bh = sW[(size_t)(kstep * 8 + ns) * 128 + l];
            short8 bl = sW[(size_t)(kstep * 8 + ns) * 128 + 64 + l];
            acc[ns] = __builtin_amdgcn_mfma_f32_16x16x32_bf16(
                ah, as_bf(bh), acc[ns], 0, 0, 0);
            acc[ns] = __builtin_amdgcn_mfma_f32_16x16x32_bf16(
                ah, as_bf(bl), acc[ns], 0, 0, 0);
            acc[ns] = __builtin_amdgcn_mfma_f32_16x16x32_bf16(
                al, as_bf(bh), acc[ns], 0, 0, 0);
        }
    }

    // ---- epilogue (fragment-major side loads; lane channel = l15*8+ns)
    union f8u { float4 v[2]; float f[8]; };
    f8u a2, v2;
    {
        const float4* p = (const float4*)(A2f + ((size_t)bi * 16 + l15) * 8);
        a2.v[0] = p[0]; a2.v[1] = p[1];
        const float4* q = (const float4*)(V2f + ((size_t)bi * 16 + l15) * 8);
        v2.v[0] = q[0]; v2.v[1] = q[1];
    }
    float h1a[8], es[8], eq[8];
    #pragma unroll
    for (int ns = 0; ns < 8; ++ns) { h1a[ns] = 0.f; es[ns] = 0.f; eq[ns] = 0.f; }

    #pragma unroll
    for (int r = 0; r < 4; ++r) {
        int j = jbase + lq * 4 + r;
        size_t fro = ((size_t)(b * VV + j) * 16 + l15) * 8;
        f8u a1, v1;
        {
            const float4* p = (const float4*)(A1f + fro);
            a1.v[0] = p[0]; a1.v[1] = p[1];
            const float4* q = (const float4*)(V1f + fro);
            v1.v[0] = q[0]; v1.v[1] = q[1];
        }
        size_t obase = ((size_t)bi * VV + j) * HH + l15 * 8;
        float en8[8];
        #pragma unroll
        for (int ns = 0; ns < 8; ++ns) {
            float en = acc[ns][r] + a1.f[ns] + a2.f[ns];
            en8[ns] = en;
            float s = sigm_(en);
            h1a[ns] = fmaf(s, v1.f[ns] + v2.f[ns], h1a[ns]);
            es[ns] += en;
            eq[ns] = fmaf(en, en, eq[ns]);
        }
        if (STOREH) {
            union { __half2 h[4]; uint4 u; } pk;
            pk.h[0] = __floats2half2_rn(en8[0], en8[1]);
            pk.h[1] = __floats2half2_rn(en8[2], en8[3]);
            pk.h[2] = __floats2half2_rn(en8[4], en8[5]);
            pk.h[3] = __floats2half2_rn(en8[6], en8[7]);
            *(uint4*)(e_newh + obase) = pk.u;
        } else {
            float4 s0 = {en8[0], en8[1], en8[2], en8[3]};
            float4 s1 = {en8[4], en8[5], en8[6], en8[7]};
            *(float4*)(e_new32 + obase) = s0;
            *(float4*)(e_new32 + obase + 4) = s1;
        }
    }

    #pragma unroll
    for (int ns = 0; ns < 8; ++ns) {
        h1a[ns] += __shfl_xor(h1a[ns], 16);
        h1a[ns] += __shfl_xor(h1a[ns], 32);
        es[ns]  += __shfl_xor(es[ns], 16);
        es[ns]  += __shfl_xor(es[ns], 32);
        eq[ns]  += __shfl_xor(eq[ns], 16);
        eq[ns]  += __shfl_xor(eq[ns], 32);
    }
    if (l < 16) {
        #pragma unroll
        for (int ns = 0; ns < 8; ++ns) {
            red[w][0][ns][l15] = h1a[ns];
            red[w][1][ns][l15] = es[ns];
            red[w][2][ns][l15] = eq[ns];
        }
    }
    __syncthreads();
    if (t < 128) {
        // thread t handles physical channel t = li*8 + ns
        int ns = t & 7, li = t >> 3;
        float h1t = 0.f, est = 0.f, eqt = 0.f;
        #pragma unroll
        for (int ww = 0; ww < 8; ++ww) {
            h1t += red[ww][0][ns][li];
            est += red[ww][1][ns][li];
            eqt += red[ww][2][ns][li];
        }
        atomicAdd(&h1acc[(size_t)bi * HH + t], h1t);
        atomicAdd(&stats[0 * HH + t], est);
        atomicAdd(&stats[1 * HH + t], eqt);
    }
}

// ---------------------------------------------------------------------------
// K4: per (b, Jtile8, Iq8): stream I; h2 partials + BN(e)+relu+residual.
// READH: read fp16 e_new from ws, write f32 e_out; else in-place f32.
// grid 1024 x 256. Thread owns (jsub=t>>5, 4 channels=(t&31)*4).
// ---------------------------------------------------------------------------
template<int READH>
__global__ __launch_bounds__(256) void k4_pass2(
    float* __restrict__ e_io,
    const unsigned short* __restrict__ e_newh,
    const float* __restrict__ e_in,
    const float* __restrict__ V1, const float* __restrict__ V2,
    const float* __restrict__ g_e, const float* __restrict__ be_e,
    float* __restrict__ h2acc,
    const float* __restrict__ stats)
{
    const int t = threadIdx.x;
    const int h4 = (t & 31) * 4;
    const int jsub = t >> 5;
    const int blk = blockIdx.x;       // ((b*32 + Jt)*8 + Iq)
    const int Iq = blk & 7;
    const int Jt = (blk >> 3) & 31;
    const int b = blk >> 8;
    const int J = Jt * 8 + jsub;
    const int bJ = (b << 8) + J;

    const float inv_n = 1.0f / (float)(BB * VV * VV);
    float sc[4], sh[4];
    #pragma unroll
    for (int c = 0; c < 4; ++c) {
        int h = h4 + c;
        float mean = stats[0 * HH + h] * inv_n;
        float var  = stats[1 * HH + h] * inv_n - mean * mean;
        float rstd = rsqrtf(var + EPS);
        sc[c] = rstd * g_e[h];
        sh[c] = be_e[h] - mean * sc[c];
    }
    float4 vh1 = *(const float4*)(V1 + (size_t)bJ * HH + h4);
    float4 h2a = {0.f, 0.f, 0.f, 0.f};

    const int I0beg = Iq * 32;
    for (int I0 = I0beg; I0 < I0beg + 32; I0 += 4) {
        float4 en[4], ei[4], v2[4];
        size_t off[4];
        #pragma unroll
        for (int u = 0; u < 4; ++u) {
            int I = I0 + u;
            off[u] = ((size_t)((b * VV + I) * VV) + J) * HH + h4;
            if (READH) {
                ushort4 eh = *(const ushort4*)(e_newh + off[u]);
                en[u].x = __half2float(__ushort_as_half(eh.x));
                en[u].y = __half2float(__ushort_as_half(eh.y));
                en[u].z = __half2float(__ushort_as_half(eh.z));
                en[u].w = __half2float(__ushort_as_half(eh.w));
            } else {
                en[u] = *(const float4*)(e_io + off[u]);
            }
            ei[u] = *(const float4*)(e_in + off[u]);
            v2[u] = *(const float4*)(V2 + (size_t)((b << 8) + I) * HH + h4);
        }
        #pragma unroll
        for (int u = 0; u < 4; ++u) {
            float4 r;
            float* enf = (float*)&en[u];
            float* eif = (float*)&ei[u];
            float* v2f = (float*)&v2[u];
            float* rf = (float*)&r;
            float* h2f = (float*)&h2a;
            float* v1f = (float*)&vh1;
            #pragma unroll
            for (int c = 0; c < 4; ++c) {
                float e_ = enf[c];
                h2f[c] = fmaf(sigm_(e_), v1f[c] + v2f[c], h2f[c]);
                float bn = fmaf(e_, sc[c], sh[c]);
                rf[c] = eif[c] + fmaxf(bn, 0.f);
            }
            *(float4*)(e_io + off[u]) = r;
        }
    }
    float* base = h2acc + (size_t)bJ * HH + h4;
    float* h2f = (float*)&h2a;
    #pragma unroll
    for (int c = 0; c < 4; ++c) atomicAdd(base + c, h2f[c]);
}

// ---------------------------------------------------------------------------
// K45: pre = U + acc; write back into acc (in place); h BN stats.
// ---------------------------------------------------------------------------
__global__ __launch_bounds__(256) void k45_combine(
    float* __restrict__ h1acc, float* __restrict__ h2acc,
    const float* __restrict__ U1, const float* __restrict__ U2,
    float* __restrict__ stats)
{
    __shared__ float red[2][2][128];
    const int t = threadIdx.x;
    const int h = t & 127;
    const int rr = t >> 7;
    const int region = blockIdx.x >> 5;
    const int r0 = (blockIdx.x & 31) * 32;
    float* acc = region ? h2acc : h1acc;
    const float* U = region ? U2 : U1;
    float s = 0.f, q = 0.f;
    #pragma unroll
    for (int rs = 0; rs < 16; ++rs) {
        size_t idx = (size_t)(r0 + rr * 16 + rs) * HH + h;
        float v = acc[idx] + U[idx];
        acc[idx] = v;
        s += v;
        q = fmaf(v, v, q);
    }
    red[0][rr][h] = s;
    red[1][rr][h] = q;
    __syncthreads();
    if (t < 128) {
        atomicAdd(&stats[(2 + 2 * region) * HH + h], red[0][0][h] + red[0][1][h]);
        atomicAdd(&stats[(3 + 2 * region) * HH + h], red[1][0][h] + red[1][1][h]);
    }
}

// ---------------------------------------------------------------------------
// K5: finalize h1_out, h2_out = x_in + relu(bn(pre)).
// ---------------------------------------------------------------------------
__global__ __launch_bounds__(256) void k5_final(
    const float* __restrict__ h1_in, const float* __restrict__ h2_in,
    const float* __restrict__ h1p, const float* __restrict__ h2p,
    const float* __restrict__ g1, const float* __restrict__ be1,
    const float* __restrict__ g2, const float* __restrict__ be2,
    float* __restrict__ out,
    const float* __restrict__ stats)
{
    const float inv_n = 1.0f / 1024.0f;
    int idx0 = blockIdx.x * 2048 + threadIdx.x;
    #pragma unroll
    for (int p = 0; p < 8; ++p) {
        int idx = idx0 + p * 256;
        int region = idx >> 17;           // 0: h1, 1: h2
        int local = idx & 131071;
        int h = idx & 127;
        float ssum = stats[(2 + 2 * region) * HH + h];
        float ssq  = stats[(3 + 2 * region) * HH + h];
        float mean = ssum * inv_n;
        float var  = ssq * inv_n - mean * mean;
        float rstd = rsqrtf(var + EPS);
        const float* g  = region ? g2 : g1;
        const float* be = region ? be2 : be1;
        float sc = rstd * g[h];
        float sh = be[h] - mean * sc;
        const float* xin = region ? h2_in : h1_in;
        const float* pre = region ? h2p : h1p;
        out[idx] = xin[local] + fmaxf(fmaf(pre[local], sc, sh), 0.f);
    }
}

// ---------------------------------------------------------------------------
extern "C" void kernel_launch(void* const* d_in, const int* in_sizes, int n_in,
                              void* d_out, int out_size, void* d_ws, size_t ws_size,
                              hipStream_t stream) {
    const float* h1   = (const float*)d_in[0];
    const float* h2   = (const float*)d_in[1];
    const float* e    = (const float*)d_in[2];
    // d_in[3] = graph (unused for sum aggregation)
    const float* W_U1 = (const float*)d_in[4];
    const float* b_U1 = (const float*)d_in[5];
    const float* W_U2 = (const float*)d_in[6];
    const float* b_U2 = (const float*)d_in[7];
    const float* W_V1 = (const float*)d_in[8];
    const float* b_V1 = (const float*)d_in[9];
    const float* W_V2 = (const float*)d_in[10];
    const float* b_V2 = (const float*)d_in[11];
    const float* W_A1 = (const float*)d_in[12];
    const float* b_A1 = (const float*)d_in[13];
    const float* W_A2 = (const float*)d_in[14];
    const float* b_A2 = (const float*)d_in[15];
    const float* W_C  = (const float*)d_in[16];
    const float* b_C  = (const float*)d_in[17];
    const float* g_h1 = (const float*)d_in[18];
    const float* be_h1= (const float*)d_in[19];
    const float* g_h2 = (const float*)d_in[20];
    const float* be_h2= (const float*)d_in[21];
    const float* g_e  = (const float*)d_in[22];
    const float* be_e = (const float*)d_in[23];

    float* ws = (float*)d_ws;
    const size_t S = (size_t)BB * VV * HH;  // 131072
    float* U1  = ws + 0 * S;
    float* U2  = ws + 1 * S;
    float* V1  = ws + 2 * S;
    float* V2  = ws + 3 * S;
    float* V1f = ws + 4 * S;
    float* V2f = ws + 5 * S;
    float* A1f = ws + 6 * S;
    float* A2f = ws + 7 * S;
    float* h1acc = ws + 8 * S;
    float* h2acc = ws + 9 * S;
    float* stats = ws + 10 * S;              // 6*128 floats
    short* Whl  = (short*)(stats + 768);     // 64 KB
    unsigned short* e_newh = (unsigned short*)(Whl + 32768);

    const size_t EN = (size_t)BB * VV * VV * HH;   // 33.55M elements
    const size_t needed = (10 * S + 768) * 4 + 65536 + EN * 2;
    const bool useh = ws_size >= needed;

    float* out = (float*)d_out;
    float* eo = out + 2 * S;                 // e region

    // zero h1acc + h2acc + stats (h1acc now accumulated via atomics)
    hipMemsetAsync(h1acc, 0, (2 * S + 768) * sizeof(float), stream);

    k0_splitW<<<8, 256, 0, stream>>>(W_C, Whl);

    LinArgs la;
    la.x1 = h1; la.x2 = h2;
    la.W[0] = W_U1; la.b[0] = b_U1; la.b2[0] = nullptr; la.out[0] = U1; la.outf[0] = nullptr;
    la.W[1] = W_V1; la.b[1] = b_V1; la.b2[1] = nullptr; la.out[1] = V1; la.outf[1] = V1f;
    la.W[2] = W_A1; la.b[2] = b_A1; la.b2[2] = b_C;     la.out[2] = nullptr; la.outf[2] = A1f;
    la.W[3] = W_U2; la.b[3] = b_U2; la.b2[3] = nullptr; la.out[3] = U2; la.outf[3] = nullptr;
    la.W[4] = W_V2; la.b[4] = b_V2; la.b2[4] = nullptr; la.out[4] = V2; la.outf[4] = V2f;
    la.W[5] = W_A2; la.b[5] = b_A2; la.b2[5] = nullptr; la.out[5] = nullptr; la.outf[5] = A2f;
    k1_linears<<<256, 128, 0, stream>>>(la);

    if (useh) {
        k2_main<1><<<BB * VV * 2, 512, 0, stream>>>(e, Whl, A1f, A2f, V1f, V2f,
                                                    eo, e_newh, h1acc, stats);
        k4_pass2<1><<<BB * 32 * 8, 256, 0, stream>>>(eo, e_newh, e, V1, V2,
                                                     g_e, be_e, h2acc, stats);
    } else {
        k2_main<0><<<BB * VV * 2, 512, 0, stream>>>(e, Whl, A1f, A2f, V1f, V2f,
                                                    eo, e_newh, h1acc, stats);
        k4_pass2<0><<<BB * 32 * 8, 256, 0, stream>>>(eo, e_newh, e, V1, V2,
                                                     g_e, be_e, h2acc, stats);
    }

    k45_combine<<<64, 256, 0, stream>>>(h1acc, h2acc, U1, U2, stats);

    k5_final<<<128, 256, 0, stream>>>(h1, h2, h1acc, h2acc,
                                      g_h1, be_h1, g_h2, be_h2, out, stats);
}

// Round 11
// 188.319 us; speedup vs baseline: 1.0323x; 1.0323x over previous
//
#include <hip/hip_runtime.h>
#include <hip/hip_fp16.h>
#include <math.h>

#define BB 4
#define VV 256
#define HH 128
#define EPS 1e-5f

typedef __attribute__((ext_vector_type(8))) short short8;
typedef __attribute__((ext_vector_type(8))) __bf16 bf16x8;
typedef __attribute__((ext_vector_type(4))) float f32x4;

__device__ __forceinline__ float sigm_(float x) {
    float ex = __builtin_amdgcn_exp2f(-1.44269504f * x);
    return __builtin_amdgcn_rcpf(1.0f + ex);
}

__device__ __forceinline__ bf16x8 as_bf(short8 s) {
    union { short8 s; bf16x8 b; } u; u.s = s; return u.b;
}

// split via native converts (RNE); lo = RNE of residual
__device__ __forceinline__ void split8n(const float4 x0, const float4 x1,
                                        bf16x8& hi, bf16x8& lo) {
    float xs[8] = {x0.x, x0.y, x0.z, x0.w, x1.x, x1.y, x1.z, x1.w};
    #pragma unroll
    for (int i = 0; i < 8; ++i) {
        float x = xs[i];
        __bf16 h = (__bf16)x;
        float r = x - (float)h;
        hi[i] = h;
        lo[i] = (__bf16)r;
    }
}

// ---------------------------------------------------------------------------
// K0: split W_C into fragment-major bf16 hi/lo planes, PERMUTED mapping:
// fragment ns, lane l15 holds W_C row n_phys = l15*8 + ns.
// short8 idx = (kstep*8+nsub)*128 + plane*64 + lane
// k = kstep*32 + ((lane>>4)&3)*8 + i
// ---------------------------------------------------------------------------
__global__ __launch_bounds__(256) void k0_splitW(const float* __restrict__ W_C,
                                                 short* __restrict__ Whl) {
    int t = blockIdx.x * 256 + threadIdx.x;   // 0..2047
    int lane = t & 63;
    int grp = t >> 6;                         // kstep*8 + nsub
    int kstep = grp >> 3, nsub = grp & 7;
    int n = (lane & 15) * 8 + nsub;           // PERMUTED channel mapping
    int kb = kstep * 32 + ((lane >> 4) & 3) * 8;
    const float4* src = (const float4*)(W_C + (size_t)n * HH + kb);
    float4 x0 = src[0], x1 = src[1];
    bf16x8 hi, lo;
    split8n(x0, x1, hi, lo);
    union { bf16x8 b; short8 s; } uh, ul;
    uh.b = hi; ul.b = lo;
    short8* dst = (short8*)Whl;
    dst[(size_t)grp * 128 + 0 * 64 + lane] = uh.s;
    dst[(size_t)grp * 128 + 1 * 64 + lane] = ul.s;
}

// ---------------------------------------------------------------------------
// K1: six small linears, 8 rows/block (grid 128). Outputs normal layout
// and/or fragment-major PERMUTED: channel h of row R stored at
// (R*16 + (h>>3))*8 + (h&7).
// ---------------------------------------------------------------------------
struct LinArgs {
    const float* x1; const float* x2;
    const float* W[6]; const float* b[6]; const float* b2[6];
    float* out[6]; float* outf[6];
};

__global__ __launch_bounds__(128) void k1_linears(LinArgs a) {
    __shared__ float xs[2][8][HH];
    const int t = threadIdx.x;
    const int r0 = blockIdx.x * 8;
    {
        const float4* s1 = (const float4*)(a.x1 + (size_t)r0 * HH);
        const float4* s2 = (const float4*)(a.x2 + (size_t)r0 * HH);
        float4* d1 = (float4*)&xs[0][0][0];
        float4* d2 = (float4*)&xs[1][0][0];
        #pragma unroll
        for (int p = 0; p < 2; ++p) {
            d1[t + p * 128] = s1[t + p * 128];
            d2[t + p * 128] = s2[t + p * 128];
        }
    }
    __syncthreads();
    const int h = t;
    const int l15h = h >> 3, nsh = h & 7;     // PERMUTED fragment position
    for (int g = 0; g < 6; ++g) {
        const float* W = a.W[g];
        const float (*x)[HH] = (g < 3) ? xs[0] : xs[1];
        float acc[8];
        #pragma unroll
        for (int r = 0; r < 8; ++r) acc[r] = 0.f;
        const float4* Wrow = (const float4*)(W + (size_t)h * HH);
        #pragma unroll 8
        for (int kq = 0; kq < 32; ++kq) {
            float4 w4 = Wrow[kq];
            #pragma unroll
            for (int r = 0; r < 8; ++r) {
                float4 ev = *(const float4*)&x[r][kq * 4];
                acc[r] = fmaf(ev.x, w4.x, acc[r]);
                acc[r] = fmaf(ev.y, w4.y, acc[r]);
                acc[r] = fmaf(ev.z, w4.z, acc[r]);
                acc[r] = fmaf(ev.w, w4.w, acc[r]);
            }
        }
        float bias = a.b[g][h];
        if (a.b2[g]) bias += a.b2[g][h];
        if (a.out[g]) {
            float* O = a.out[g] + (size_t)r0 * HH + h;
            #pragma unroll
            for (int r = 0; r < 8; ++r) O[(size_t)r * HH] = acc[r] + bias;
        }
        if (a.outf[g]) {
            float* Of = a.outf[g];
            #pragma unroll
            for (int r = 0; r < 8; ++r)
                Of[((size_t)(r0 + r) * 16 + l15h) * 8 + nsh] = acc[r] + bias;
        }
    }
}

// ---------------------------------------------------------------------------
// K2: per (b,i,jhalf): e_new = e@W_C^T + A1f + A2f; packed-fp16/f32 store;
// h1 partial agg (atomic) + e BN stats. 512 thr = 8 waves, wave w covers
// j in [jhalf*128 + w*16, +16), n full 128. acc = 32 AGPR.
// FULL-K e PRELOAD: lane's entire K-range (8 float4 = 32 VGPR) issued
// BEFORE W staging -> HBM latency hidden under staging + barrier; k-loop
// has zero global loads. Full W (64 KB) in LDS.
// ---------------------------------------------------------------------------
template<int STOREH>
__global__ __launch_bounds__(512, 4) void k2_main(
    const float* __restrict__ e,
    const short* __restrict__ Whl,
    const float* __restrict__ A1f, const float* __restrict__ A2f,
    const float* __restrict__ V1f, const float* __restrict__ V2f,
    float* __restrict__ e_new32,
    unsigned short* __restrict__ e_newh,
    float* __restrict__ h1acc,
    float* __restrict__ stats)
{
    __shared__ short8 sW[4096];          // 64 KB: full W hi/lo
    __shared__ float red[8][3][8][16];   // 12 KB [wave][qty][ns][l15]
    const int t = threadIdx.x;
    const int l = t & 63;
    const int w = t >> 6;
    const int l15 = l & 15;
    const int lq = (l >> 4) & 3;
    const int blk = blockIdx.x;
    const int bi = blk >> 1;             // b*V + i
    const int jhalf = blk & 1;
    const int b = bi >> 8;
    const int jbase = jhalf * 128 + w * 16;

    // ---- issue ALL e loads first (8 float4/lane, ride out HBM latency)
    const float* pa = e + (size_t)bi * (VV * HH) +
                      (size_t)(jbase + l15) * HH + lq * 8;
    float4 ec[8];
    #pragma unroll
    for (int kstep = 0; kstep < 4; ++kstep) {
        ec[2 * kstep]     = *(const float4*)(pa + kstep * 32);
        ec[2 * kstep + 1] = *(const float4*)(pa + kstep * 32 + 4);
    }

    // ---- stage W into LDS
    {
        const short8* src = (const short8*)Whl;
        #pragma unroll
        for (int p = 0; p < 8; ++p) sW[p * 512 + t] = src[p * 512 + t];
    }
    __syncthreads();

    f32x4 acc[8];
    #pragma unroll
    for (int ns = 0; ns < 8; ++ns) acc[ns] = (f32x4){0.f, 0.f, 0.f, 0.f};

    #pragma unroll
    for (int kstep = 0; kstep < 4; ++kstep) {
        bf16x8 ah, al;
        split8n(ec[2 * kstep], ec[2 * kstep + 1], ah, al);
        #pragma unroll
        for (int ns = 0; ns < 8; ++ns) {
            short8 bh = sW[(size_t)(kstep * 8 + ns) * 128 + l];
            short8 bl = sW[(size_t)(kstep * 8 + ns) * 128 + 64 + l];
            acc[ns] = __builtin_amdgcn_mfma_f32_16x16x32_bf16(
                ah, as_bf(bh), acc[ns], 0, 0, 0);
            acc[ns] = __builtin_amdgcn_mfma_f32_16x16x32_bf16(
                ah, as_bf(bl), acc[ns], 0, 0, 0);
            acc[ns] = __builtin_amdgcn_mfma_f32_16x16x32_bf16(
                al, as_bf(bh), acc[ns], 0, 0, 0);
        }
    }

    // ---- epilogue (fragment-major side loads; lane channel = l15*8+ns)
    union f8u { float4 v[2]; float f[8]; };
    f8u a2, v2;
    {
        const float4* p = (const float4*)(A2f + ((size_t)bi * 16 + l15) * 8);
        a2.v[0] = p[0]; a2.v[1] = p[1];
        const float4* q = (const float4*)(V2f + ((size_t)bi * 16 + l15) * 8);
        v2.v[0] = q[0]; v2.v[1] = q[1];
    }
    float h1a[8], es[8], eq[8];
    #pragma unroll
    for (int ns = 0; ns < 8; ++ns) { h1a[ns] = 0.f; es[ns] = 0.f; eq[ns] = 0.f; }

    #pragma unroll
    for (int r = 0; r < 4; ++r) {
        int j = jbase + lq * 4 + r;
        size_t fro = ((size_t)(b * VV + j) * 16 + l15) * 8;
        f8u a1, v1;
        {
            const float4* p = (const float4*)(A1f + fro);
            a1.v[0] = p[0]; a1.v[1] = p[1];
            const float4* q = (const float4*)(V1f + fro);
            v1.v[0] = q[0]; v1.v[1] = q[1];
        }
        size_t obase = ((size_t)bi * VV + j) * HH + l15 * 8;
        float en8[8];
        #pragma unroll
        for (int ns = 0; ns < 8; ++ns) {
            float en = acc[ns][r] + a1.f[ns] + a2.f[ns];
            en8[ns] = en;
            float s = sigm_(en);
            h1a[ns] = fmaf(s, v1.f[ns] + v2.f[ns], h1a[ns]);
            es[ns] += en;
            eq[ns] = fmaf(en, en, eq[ns]);
        }
        if (STOREH) {
            union { __half2 h[4]; uint4 u; } pk;
            pk.h[0] = __floats2half2_rn(en8[0], en8[1]);
            pk.h[1] = __floats2half2_rn(en8[2], en8[3]);
            pk.h[2] = __floats2half2_rn(en8[4], en8[5]);
            pk.h[3] = __floats2half2_rn(en8[6], en8[7]);
            *(uint4*)(e_newh + obase) = pk.u;
        } else {
            float4 s0 = {en8[0], en8[1], en8[2], en8[3]};
            float4 s1 = {en8[4], en8[5], en8[6], en8[7]};
            *(float4*)(e_new32 + obase) = s0;
            *(float4*)(e_new32 + obase + 4) = s1;
        }
    }

    #pragma unroll
    for (int ns = 0; ns < 8; ++ns) {
        h1a[ns] += __shfl_xor(h1a[ns], 16);
        h1a[ns] += __shfl_xor(h1a[ns], 32);
        es[ns]  += __shfl_xor(es[ns], 16);
        es[ns]  += __shfl_xor(es[ns], 32);
        eq[ns]  += __shfl_xor(eq[ns], 16);
        eq[ns]  += __shfl_xor(eq[ns], 32);
    }
    if (l < 16) {
        #pragma unroll
        for (int ns = 0; ns < 8; ++ns) {
            red[w][0][ns][l15] = h1a[ns];
            red[w][1][ns][l15] = es[ns];
            red[w][2][ns][l15] = eq[ns];
        }
    }
    __syncthreads();
    if (t < 128) {
        // thread t handles physical channel t = li*8 + ns
        int ns = t & 7, li = t >> 3;
        float h1t = 0.f, est = 0.f, eqt = 0.f;
        #pragma unroll
        for (int ww = 0; ww < 8; ++ww) {
            h1t += red[ww][0][ns][li];
            est += red[ww][1][ns][li];
            eqt += red[ww][2][ns][li];
        }
        atomicAdd(&h1acc[(size_t)bi * HH + t], h1t);
        atomicAdd(&stats[0 * HH + t], est);
        atomicAdd(&stats[1 * HH + t], eqt);
    }
}

// ---------------------------------------------------------------------------
// K4: per (b, Jtile8, Iq8): stream I; h2 partials + BN(e)+relu+residual.
// READH: read fp16 e_new from ws, write f32 e_out; else in-place f32.
// grid 1024 x 256. Thread owns (jsub=t>>5, 4 channels=(t&31)*4).
// ---------------------------------------------------------------------------
template<int READH>
__global__ __launch_bounds__(256) void k4_pass2(
    float* __restrict__ e_io,
    const unsigned short* __restrict__ e_newh,
    const float* __restrict__ e_in,
    const float* __restrict__ V1, const float* __restrict__ V2,
    const float* __restrict__ g_e, const float* __restrict__ be_e,
    float* __restrict__ h2acc,
    const float* __restrict__ stats)
{
    const int t = threadIdx.x;
    const int h4 = (t & 31) * 4;
    const int jsub = t >> 5;
    const int blk = blockIdx.x;       // ((b*32 + Jt)*8 + Iq)
    const int Iq = blk & 7;
    const int Jt = (blk >> 3) & 31;
    const int b = blk >> 8;
    const int J = Jt * 8 + jsub;
    const int bJ = (b << 8) + J;

    const float inv_n = 1.0f / (float)(BB * VV * VV);
    float sc[4], sh[4];
    #pragma unroll
    for (int c = 0; c < 4; ++c) {
        int h = h4 + c;
        float mean = stats[0 * HH + h] * inv_n;
        float var  = stats[1 * HH + h] * inv_n - mean * mean;
        float rstd = rsqrtf(var + EPS);
        sc[c] = rstd * g_e[h];
        sh[c] = be_e[h] - mean * sc[c];
    }
    float4 vh1 = *(const float4*)(V1 + (size_t)bJ * HH + h4);
    float4 h2a = {0.f, 0.f, 0.f, 0.f};

    const int I0beg = Iq * 32;
    for (int I0 = I0beg; I0 < I0beg + 32; I0 += 4) {
        float4 en[4], ei[4], v2[4];
        size_t off[4];
        #pragma unroll
        for (int u = 0; u < 4; ++u) {
            int I = I0 + u;
            off[u] = ((size_t)((b * VV + I) * VV) + J) * HH + h4;
            if (READH) {
                ushort4 eh = *(const ushort4*)(e_newh + off[u]);
                en[u].x = __half2float(__ushort_as_half(eh.x));
                en[u].y = __half2float(__ushort_as_half(eh.y));
                en[u].z = __half2float(__ushort_as_half(eh.z));
                en[u].w = __half2float(__ushort_as_half(eh.w));
            } else {
                en[u] = *(const float4*)(e_io + off[u]);
            }
            ei[u] = *(const float4*)(e_in + off[u]);
            v2[u] = *(const float4*)(V2 + (size_t)((b << 8) + I) * HH + h4);
        }
        #pragma unroll
        for (int u = 0; u < 4; ++u) {
            float4 r;
            float* enf = (float*)&en[u];
            float* eif = (float*)&ei[u];
            float* v2f = (float*)&v2[u];
            float* rf = (float*)&r;
            float* h2f = (float*)&h2a;
            float* v1f = (float*)&vh1;
            #pragma unroll
            for (int c = 0; c < 4; ++c) {
                float e_ = enf[c];
                h2f[c] = fmaf(sigm_(e_), v1f[c] + v2f[c], h2f[c]);
                float bn = fmaf(e_, sc[c], sh[c]);
                rf[c] = eif[c] + fmaxf(bn, 0.f);
            }
            *(float4*)(e_io + off[u]) = r;
        }
    }
    float* base = h2acc + (size_t)bJ * HH + h4;
    float* h2f = (float*)&h2a;
    #pragma unroll
    for (int c = 0; c < 4; ++c) atomicAdd(base + c, h2f[c]);
}

// ---------------------------------------------------------------------------
// K45: pre = U + acc; write back into acc (in place); h BN stats.
// ---------------------------------------------------------------------------
__global__ __launch_bounds__(256) void k45_combine(
    float* __restrict__ h1acc, float* __restrict__ h2acc,
    const float* __restrict__ U1, const float* __restrict__ U2,
    float* __restrict__ stats)
{
    __shared__ float red[2][2][128];
    const int t = threadIdx.x;
    const int h = t & 127;
    const int rr = t >> 7;
    const int region = blockIdx.x >> 5;
    const int r0 = (blockIdx.x & 31) * 32;
    float* acc = region ? h2acc : h1acc;
    const float* U = region ? U2 : U1;
    float s = 0.f, q = 0.f;
    #pragma unroll
    for (int rs = 0; rs < 16; ++rs) {
        size_t idx = (size_t)(r0 + rr * 16 + rs) * HH + h;
        float v = acc[idx] + U[idx];
        acc[idx] = v;
        s += v;
        q = fmaf(v, v, q);
    }
    red[0][rr][h] = s;
    red[1][rr][h] = q;
    __syncthreads();
    if (t < 128) {
        atomicAdd(&stats[(2 + 2 * region) * HH + h], red[0][0][h] + red[0][1][h]);
        atomicAdd(&stats[(3 + 2 * region) * HH + h], red[1][0][h] + red[1][1][h]);
    }
}

// ---------------------------------------------------------------------------
// K5: finalize h1_out, h2_out = x_in + relu(bn(pre)).
// ---------------------------------------------------------------------------
__global__ __launch_bounds__(256) void k5_final(
    const float* __restrict__ h1_in, const float* __restrict__ h2_in,
    const float* __restrict__ h1p, const float* __restrict__ h2p,
    const float* __restrict__ g1, const float* __restrict__ be1,
    const float* __restrict__ g2, const float* __restrict__ be2,
    float* __restrict__ out,
    const float* __restrict__ stats)
{
    const float inv_n = 1.0f / 1024.0f;
    int idx0 = blockIdx.x * 2048 + threadIdx.x;
    #pragma unroll
    for (int p = 0; p < 8; ++p) {
        int idx = idx0 + p * 256;
        int region = idx >> 17;           // 0: h1, 1: h2
        int local = idx & 131071;
        int h = idx & 127;
        float ssum = stats[(2 + 2 * region) * HH + h];
        float ssq  = stats[(3 + 2 * region) * HH + h];
        float mean = ssum * inv_n;
        float var  = ssq * inv_n - mean * mean;
        float rstd = rsqrtf(var + EPS);
        const float* g  = region ? g2 : g1;
        const float* be = region ? be2 : be1;
        float sc = rstd * g[h];
        float sh = be[h] - mean * sc;
        const float* xin = region ? h2_in : h1_in;
        const float* pre = region ? h2p : h1p;
        out[idx] = xin[local] + fmaxf(fmaf(pre[local], sc, sh), 0.f);
    }
}

// ---------------------------------------------------------------------------
extern "C" void kernel_launch(void* const* d_in, const int* in_sizes, int n_in,
                              void* d_out, int out_size, void* d_ws, size_t ws_size,
                              hipStream_t stream) {
    const float* h1   = (const float*)d_in[0];
    const float* h2   = (const float*)d_in[1];
    const float* e    = (const float*)d_in[2];
    // d_in[3] = graph (unused for sum aggregation)
    const float* W_U1 = (const float*)d_in[4];
    const float* b_U1 = (const float*)d_in[5];
    const float* W_U2 = (const float*)d_in[6];
    const float* b_U2 = (const float*)d_in[7];
    const float* W_V1 = (const float*)d_in[8];
    const float* b_V1 = (const float*)d_in[9];
    const float* W_V2 = (const float*)d_in[10];
    const float* b_V2 = (const float*)d_in[11];
    const float* W_A1 = (const float*)d_in[12];
    const float* b_A1 = (const float*)d_in[13];
    const float* W_A2 = (const float*)d_in[14];
    const float* b_A2 = (const float*)d_in[15];
    const float* W_C  = (const float*)d_in[16];
    const float* b_C  = (const float*)d_in[17];
    const float* g_h1 = (const float*)d_in[18];
    const float* be_h1= (const float*)d_in[19];
    const float* g_h2 = (const float*)d_in[20];
    const float* be_h2= (const float*)d_in[21];
    const float* g_e  = (const float*)d_in[22];
    const float* be_e = (const float*)d_in[23];

    float* ws = (float*)d_ws;
    const size_t S = (size_t)BB * VV * HH;  // 131072
    float* U1  = ws + 0 * S;
    float* U2  = ws + 1 * S;
    float* V1  = ws + 2 * S;
    float* V2  = ws + 3 * S;
    float* V1f = ws + 4 * S;
    float* V2f = ws + 5 * S;
    float* A1f = ws + 6 * S;
    float* A2f = ws + 7 * S;
    float* h1acc = ws + 8 * S;
    float* h2acc = ws + 9 * S;
    float* stats = ws + 10 * S;              // 6*128 floats
    short* Whl  = (short*)(stats + 768);     // 64 KB
    unsigned short* e_newh = (unsigned short*)(Whl + 32768);

    const size_t EN = (size_t)BB * VV * VV * HH;   // 33.55M elements
    const size_t needed = (10 * S + 768) * 4 + 65536 + EN * 2;
    const bool useh = ws_size >= needed;

    float* out = (float*)d_out;
    float* eo = out + 2 * S;                 // e region

    // zero h1acc + h2acc + stats (h1acc accumulated via atomics)
    hipMemsetAsync(h1acc, 0, (2 * S + 768) * sizeof(float), stream);

    k0_splitW<<<8, 256, 0, stream>>>(W_C, Whl);

    LinArgs la;
    la.x1 = h1; la.x2 = h2;
    la.W[0] = W_U1; la.b[0] = b_U1; la.b2[0] = nullptr; la.out[0] = U1; la.outf[0] = nullptr;
    la.W[1] = W_V1; la.b[1] = b_V1; la.b2[1] = nullptr; la.out[1] = V1; la.outf[1] = V1f;
    la.W[2] = W_A1; la.b[2] = b_A1; la.b2[2] = b_C;     la.out[2] = nullptr; la.outf[2] = A1f;
    la.W[3] = W_U2; la.b[3] = b_U2; la.b2[3] = nullptr; la.out[3] = U2; la.outf[3] = nullptr;
    la.W[4] = W_V2; la.b[4] = b_V2; la.b2[4] = nullptr; la.out[4] = V2; la.outf[4] = V2f;
    la.W[5] = W_A2; la.b[5] = b_A2; la.b2[5] = nullptr; la.out[5] = nullptr; la.outf[5] = A2f;
    k1_linears<<<128, 128, 0, stream>>>(la);

    if (useh) {
        k2_main<1><<<BB * VV * 2, 512, 0, stream>>>(e, Whl, A1f, A2f, V1f, V2f,
                                                    eo, e_newh, h1acc, stats);
        k4_pass2<1><<<BB * 32 * 8, 256, 0, stream>>>(eo, e_newh, e, V1, V2,
                                                     g_e, be_e, h2acc, stats);
    } else {
        k2_main<0><<<BB * VV * 2, 512, 0, stream>>>(e, Whl, A1f, A2f, V1f, V2f,
                                                    eo, e_newh, h1acc, stats);
        k4_pass2<0><<<BB * 32 * 8, 256, 0, stream>>>(eo, e_newh, e, V1, V2,
                                                     g_e, be_e, h2acc, stats);
    }

    k45_combine<<<64, 256, 0, stream>>>(h1acc, h2acc, U1, U2, stats);

    k5_final<<<128, 256, 0, stream>>>(h1, h2, h1acc, h2acc,
                                      g_h1, be_h1, g_h2, be_h2, out, stats);
}

// Round 12
// 187.142 us; speedup vs baseline: 1.0388x; 1.0063x over previous
//
#include <hip/hip_runtime.h>
#include <hip/hip_fp16.h>
#include <math.h>

#define BB 4
#define VV 256
#define HH 128
#define EPS 1e-5f

typedef __attribute__((ext_vector_type(8))) short short8;
typedef __attribute__((ext_vector_type(8))) __bf16 bf16x8;
typedef __attribute__((ext_vector_type(4))) float f32x4;

__device__ __forceinline__ float sigm_(float x) {
    float ex = __builtin_amdgcn_exp2f(-1.44269504f * x);
    return __builtin_amdgcn_rcpf(1.0f + ex);
}

__device__ __forceinline__ bf16x8 as_bf(short8 s) {
    union { short8 s; bf16x8 b; } u; u.s = s; return u.b;
}

// split via native converts (RNE); lo = RNE of residual
__device__ __forceinline__ void split8n(const float4 x0, const float4 x1,
                                        bf16x8& hi, bf16x8& lo) {
    float xs[8] = {x0.x, x0.y, x0.z, x0.w, x1.x, x1.y, x1.z, x1.w};
    #pragma unroll
    for (int i = 0; i < 8; ++i) {
        float x = xs[i];
        __bf16 h = (__bf16)x;
        float r = x - (float)h;
        hi[i] = h;
        lo[i] = (__bf16)r;
    }
}

// ---------------------------------------------------------------------------
// K1 fused: blocks 0-127: six linears (8 rows each). Blocks 128-143: W_C
// split into fragment-major bf16 hi/lo planes (PERMUTED: fragment ns, lane
// l15 holds W_C row n_phys = l15*8+ns). ALL blocks: grid-stride zero of
// h1acc/h2acc/stats.
// ---------------------------------------------------------------------------
struct LinArgs {
    const float* x1; const float* x2;
    const float* W[6]; const float* b[6]; const float* b2[6];
    float* out[6]; float* outf[6];
};

__global__ __launch_bounds__(128) void k1_fused(LinArgs a,
                                                const float* __restrict__ W_C,
                                                short* __restrict__ Whl,
                                                float4* __restrict__ zbase,
                                                int nz4) {
    const int blk = blockIdx.x;
    const int tid = threadIdx.x;
    // zero slice (all 144 blocks)
    {
        int gtid = blk * 128 + tid;
        float4 z = {0.f, 0.f, 0.f, 0.f};
        for (int i = gtid; i < nz4; i += 144 * 128) zbase[i] = z;
    }
    if (blk >= 128) {
        // W split: t in [0, 2048)
        int t = (blk - 128) * 128 + tid;
        int lane = t & 63;
        int grp = t >> 6;                     // kstep*8 + nsub
        int kstep = grp >> 3, nsub = grp & 7;
        int n = (lane & 15) * 8 + nsub;       // PERMUTED channel mapping
        int kb = kstep * 32 + ((lane >> 4) & 3) * 8;
        const float4* src = (const float4*)(W_C + (size_t)n * HH + kb);
        float4 x0 = src[0], x1 = src[1];
        bf16x8 hi, lo;
        split8n(x0, x1, hi, lo);
        union { bf16x8 b; short8 s; } uh, ul;
        uh.b = hi; ul.b = lo;
        short8* dst = (short8*)Whl;
        dst[(size_t)grp * 128 + 0 * 64 + lane] = uh.s;
        dst[(size_t)grp * 128 + 1 * 64 + lane] = ul.s;
        return;
    }
    // ---- six linears
    __shared__ float xs[2][8][HH];
    const int t = tid;
    const int r0 = blk * 8;
    {
        const float4* s1 = (const float4*)(a.x1 + (size_t)r0 * HH);
        const float4* s2 = (const float4*)(a.x2 + (size_t)r0 * HH);
        float4* d1 = (float4*)&xs[0][0][0];
        float4* d2 = (float4*)&xs[1][0][0];
        #pragma unroll
        for (int p = 0; p < 2; ++p) {
            d1[t + p * 128] = s1[t + p * 128];
            d2[t + p * 128] = s2[t + p * 128];
        }
    }
    __syncthreads();
    const int h = t;
    const int l15h = h >> 3, nsh = h & 7;     // PERMUTED fragment position
    for (int g = 0; g < 6; ++g) {
        const float* W = a.W[g];
        const float (*x)[HH] = (g < 3) ? xs[0] : xs[1];
        float acc[8];
        #pragma unroll
        for (int r = 0; r < 8; ++r) acc[r] = 0.f;
        const float4* Wrow = (const float4*)(W + (size_t)h * HH);
        #pragma unroll 8
        for (int kq = 0; kq < 32; ++kq) {
            float4 w4 = Wrow[kq];
            #pragma unroll
            for (int r = 0; r < 8; ++r) {
                float4 ev = *(const float4*)&x[r][kq * 4];
                acc[r] = fmaf(ev.x, w4.x, acc[r]);
                acc[r] = fmaf(ev.y, w4.y, acc[r]);
                acc[r] = fmaf(ev.z, w4.z, acc[r]);
                acc[r] = fmaf(ev.w, w4.w, acc[r]);
            }
        }
        float bias = a.b[g][h];
        if (a.b2[g]) bias += a.b2[g][h];
        if (a.out[g]) {
            float* O = a.out[g] + (size_t)r0 * HH + h;
            #pragma unroll
            for (int r = 0; r < 8; ++r) O[(size_t)r * HH] = acc[r] + bias;
        }
        if (a.outf[g]) {
            float* Of = a.outf[g];
            #pragma unroll
            for (int r = 0; r < 8; ++r)
                Of[((size_t)(r0 + r) * 16 + l15h) * 8 + nsh] = acc[r] + bias;
        }
    }
}

// ---------------------------------------------------------------------------
// K2: per (b,i,jhalf): e_new = e@W_C^T + A1f + A2f; packed-fp16/f32 store;
// h1 partial agg (atomic) + e BN stats. 512 thr = 8 waves, wave w covers
// j in [jhalf*128 + w*16, +16), n full 128. acc = 32 AGPR. Full-K e preload
// (8 float4/lane) issued before W staging. setprio(1) around MFMA loop.
// ---------------------------------------------------------------------------
template<int STOREH>
__global__ __launch_bounds__(512, 4) void k2_main(
    const float* __restrict__ e,
    const short* __restrict__ Whl,
    const float* __restrict__ A1f, const float* __restrict__ A2f,
    const float* __restrict__ V1f, const float* __restrict__ V2f,
    float* __restrict__ e_new32,
    unsigned short* __restrict__ e_newh,
    float* __restrict__ h1acc,
    float* __restrict__ stats)
{
    __shared__ short8 sW[4096];          // 64 KB: full W hi/lo
    __shared__ float red[8][3][8][16];   // 12 KB [wave][qty][ns][l15]
    const int t = threadIdx.x;
    const int l = t & 63;
    const int w = t >> 6;
    const int l15 = l & 15;
    const int lq = (l >> 4) & 3;
    const int blk = blockIdx.x;
    const int bi = blk >> 1;             // b*V + i
    const int jhalf = blk & 1;
    const int b = bi >> 8;
    const int jbase = jhalf * 128 + w * 16;

    // ---- issue ALL e loads first (8 float4/lane, ride out HBM latency)
    const float* pa = e + (size_t)bi * (VV * HH) +
                      (size_t)(jbase + l15) * HH + lq * 8;
    float4 ec[8];
    #pragma unroll
    for (int kstep = 0; kstep < 4; ++kstep) {
        ec[2 * kstep]     = *(const float4*)(pa + kstep * 32);
        ec[2 * kstep + 1] = *(const float4*)(pa + kstep * 32 + 4);
    }

    // ---- stage W into LDS
    {
        const short8* src = (const short8*)Whl;
        #pragma unroll
        for (int p = 0; p < 8; ++p) sW[p * 512 + t] = src[p * 512 + t];
    }
    __syncthreads();

    f32x4 acc[8];
    #pragma unroll
    for (int ns = 0; ns < 8; ++ns) acc[ns] = (f32x4){0.f, 0.f, 0.f, 0.f};

    __builtin_amdgcn_s_setprio(1);
    #pragma unroll
    for (int kstep = 0; kstep < 4; ++kstep) {
        bf16x8 ah, al;
        split8n(ec[2 * kstep], ec[2 * kstep + 1], ah, al);
        #pragma unroll
        for (int ns = 0; ns < 8; ++ns) {
            short8 bh = sW[(size_t)(kstep * 8 + ns) * 128 + l];
            short8 bl = sW[(size_t)(kstep * 8 + ns) * 128 + 64 + l];
            acc[ns] = __builtin_amdgcn_mfma_f32_16x16x32_bf16(
                ah, as_bf(bh), acc[ns], 0, 0, 0);
            acc[ns] = __builtin_amdgcn_mfma_f32_16x16x32_bf16(
                ah, as_bf(bl), acc[ns], 0, 0, 0);
            acc[ns] = __builtin_amdgcn_mfma_f32_16x16x32_bf16(
                al, as_bf(bh), acc[ns], 0, 0, 0);
        }
    }
    __builtin_amdgcn_s_setprio(0);

    // ---- epilogue (fragment-major side loads; lane channel = l15*8+ns)
    union f8u { float4 v[2]; float f[8]; };
    f8u a2, v2;
    {
        const float4* p = (const float4*)(A2f + ((size_t)bi * 16 + l15) * 8);
        a2.v[0] = p[0]; a2.v[1] = p[1];
        const float4* q = (const float4*)(V2f + ((size_t)bi * 16 + l15) * 8);
        v2.v[0] = q[0]; v2.v[1] = q[1];
    }
    float h1a[8], es[8], eq[8];
    #pragma unroll
    for (int ns = 0; ns < 8; ++ns) { h1a[ns] = 0.f; es[ns] = 0.f; eq[ns] = 0.f; }

    #pragma unroll
    for (int r = 0; r < 4; ++r) {
        int j = jbase + lq * 4 + r;
        size_t fro = ((size_t)(b * VV + j) * 16 + l15) * 8;
        f8u a1, v1;
        {
            const float4* p = (const float4*)(A1f + fro);
            a1.v[0] = p[0]; a1.v[1] = p[1];
            const float4* q = (const float4*)(V1f + fro);
            v1.v[0] = q[0]; v1.v[1] = q[1];
        }
        size_t obase = ((size_t)bi * VV + j) * HH + l15 * 8;
        float en8[8];
        #pragma unroll
        for (int ns = 0; ns < 8; ++ns) {
            float en = acc[ns][r] + a1.f[ns] + a2.f[ns];
            en8[ns] = en;
            float s = sigm_(en);
            h1a[ns] = fmaf(s, v1.f[ns] + v2.f[ns], h1a[ns]);
            es[ns] += en;
            eq[ns] = fmaf(en, en, eq[ns]);
        }
        if (STOREH) {
            union { __half2 h[4]; uint4 u; } pk;
            pk.h[0] = __floats2half2_rn(en8[0], en8[1]);
            pk.h[1] = __floats2half2_rn(en8[2], en8[3]);
            pk.h[2] = __floats2half2_rn(en8[4], en8[5]);
            pk.h[3] = __floats2half2_rn(en8[6], en8[7]);
            *(uint4*)(e_newh + obase) = pk.u;
        } else {
            float4 s0 = {en8[0], en8[1], en8[2], en8[3]};
            float4 s1 = {en8[4], en8[5], en8[6], en8[7]};
            *(float4*)(e_new32 + obase) = s0;
            *(float4*)(e_new32 + obase + 4) = s1;
        }
    }

    #pragma unroll
    for (int ns = 0; ns < 8; ++ns) {
        h1a[ns] += __shfl_xor(h1a[ns], 16);
        h1a[ns] += __shfl_xor(h1a[ns], 32);
        es[ns]  += __shfl_xor(es[ns], 16);
        es[ns]  += __shfl_xor(es[ns], 32);
        eq[ns]  += __shfl_xor(eq[ns], 16);
        eq[ns]  += __shfl_xor(eq[ns], 32);
    }
    if (l < 16) {
        #pragma unroll
        for (int ns = 0; ns < 8; ++ns) {
            red[w][0][ns][l15] = h1a[ns];
            red[w][1][ns][l15] = es[ns];
            red[w][2][ns][l15] = eq[ns];
        }
    }
    __syncthreads();
    if (t < 128) {
        // thread t handles physical channel t = li*8 + ns
        int ns = t & 7, li = t >> 3;
        float h1t = 0.f, est = 0.f, eqt = 0.f;
        #pragma unroll
        for (int ww = 0; ww < 8; ++ww) {
            h1t += red[ww][0][ns][li];
            est += red[ww][1][ns][li];
            eqt += red[ww][2][ns][li];
        }
        atomicAdd(&h1acc[(size_t)bi * HH + t], h1t);
        atomicAdd(&stats[0 * HH + t], est);
        atomicAdd(&stats[1 * HH + t], eqt);
    }
}

// ---------------------------------------------------------------------------
// K4: blocks <1024: per (b, Jtile8, Iq8) stream I; h2 partials +
// BN(e)+relu+residual. Blocks >=1024 (32 blocks): h1 finalize
// (pre = U1 + h1acc in place, h1 BN stats) — h1acc complete since k2 done.
// ---------------------------------------------------------------------------
template<int READH>
__global__ __launch_bounds__(256) void k4_pass2(
    float* __restrict__ e_io,
    const unsigned short* __restrict__ e_newh,
    const float* __restrict__ e_in,
    const float* __restrict__ V1, const float* __restrict__ V2,
    const float* __restrict__ g_e, const float* __restrict__ be_e,
    float* __restrict__ h2acc,
    float* __restrict__ h1acc, const float* __restrict__ U1,
    float* __restrict__ stats)
{
    __shared__ float red[2][2][128];
    const int t = threadIdx.x;
    const int blk = blockIdx.x;

    if (blk >= 1024) {
        // ---- h1 finalize (k45 region 0): 32 blocks x 32 rows
        const int rb = blk - 1024;
        const int h = t & 127;
        const int rr = t >> 7;
        const int r0 = rb * 32;
        float s = 0.f, q = 0.f;
        #pragma unroll
        for (int rs = 0; rs < 16; ++rs) {
            size_t idx = (size_t)(r0 + rr * 16 + rs) * HH + h;
            float v = h1acc[idx] + U1[idx];
            h1acc[idx] = v;
            s += v;
            q = fmaf(v, v, q);
        }
        red[0][rr][h] = s;
        red[1][rr][h] = q;
        __syncthreads();
        if (t < 128) {
            atomicAdd(&stats[2 * HH + h], red[0][0][h] + red[0][1][h]);
            atomicAdd(&stats[3 * HH + h], red[1][0][h] + red[1][1][h]);
        }
        return;
    }

    const int h4 = (t & 31) * 4;
    const int jsub = t >> 5;
    const int Iq = blk & 7;
    const int Jt = (blk >> 3) & 31;
    const int b = blk >> 8;
    const int J = Jt * 8 + jsub;
    const int bJ = (b << 8) + J;

    const float inv_n = 1.0f / (float)(BB * VV * VV);
    float sc[4], sh[4];
    #pragma unroll
    for (int c = 0; c < 4; ++c) {
        int h = h4 + c;
        float mean = stats[0 * HH + h] * inv_n;
        float var  = stats[1 * HH + h] * inv_n - mean * mean;
        float rstd = rsqrtf(var + EPS);
        sc[c] = rstd * g_e[h];
        sh[c] = be_e[h] - mean * sc[c];
    }
    float4 vh1 = *(const float4*)(V1 + (size_t)bJ * HH + h4);
    float4 h2a = {0.f, 0.f, 0.f, 0.f};

    const int I0beg = Iq * 32;
    for (int I0 = I0beg; I0 < I0beg + 32; I0 += 4) {
        float4 en[4], ei[4], v2[4];
        size_t off[4];
        #pragma unroll
        for (int u = 0; u < 4; ++u) {
            int I = I0 + u;
            off[u] = ((size_t)((b * VV + I) * VV) + J) * HH + h4;
            if (READH) {
                ushort4 eh = *(const ushort4*)(e_newh + off[u]);
                en[u].x = __half2float(__ushort_as_half(eh.x));
                en[u].y = __half2float(__ushort_as_half(eh.y));
                en[u].z = __half2float(__ushort_as_half(eh.z));
                en[u].w = __half2float(__ushort_as_half(eh.w));
            } else {
                en[u] = *(const float4*)(e_io + off[u]);
            }
            ei[u] = *(const float4*)(e_in + off[u]);
            v2[u] = *(const float4*)(V2 + (size_t)((b << 8) + I) * HH + h4);
        }
        #pragma unroll
        for (int u = 0; u < 4; ++u) {
            float4 r;
            float* enf = (float*)&en[u];
            float* eif = (float*)&ei[u];
            float* v2f = (float*)&v2[u];
            float* rf = (float*)&r;
            float* h2f = (float*)&h2a;
            float* v1f = (float*)&vh1;
            #pragma unroll
            for (int c = 0; c < 4; ++c) {
                float e_ = enf[c];
                h2f[c] = fmaf(sigm_(e_), v1f[c] + v2f[c], h2f[c]);
                float bn = fmaf(e_, sc[c], sh[c]);
                rf[c] = eif[c] + fmaxf(bn, 0.f);
            }
            *(float4*)(e_io + off[u]) = r;
        }
    }
    float* base = h2acc + (size_t)bJ * HH + h4;
    float* h2f = (float*)&h2a;
    #pragma unroll
    for (int c = 0; c < 4; ++c) atomicAdd(base + c, h2f[c]);
}

// ---------------------------------------------------------------------------
// K45h2: pre = U2 + h2acc in place; h2 BN stats. 32 blocks x 32 rows.
// ---------------------------------------------------------------------------
__global__ __launch_bounds__(256) void k45_h2(
    float* __restrict__ h2acc, const float* __restrict__ U2,
    float* __restrict__ stats)
{
    __shared__ float red[2][2][128];
    const int t = threadIdx.x;
    const int h = t & 127;
    const int rr = t >> 7;
    const int r0 = blockIdx.x * 32;
    float s = 0.f, q = 0.f;
    #pragma unroll
    for (int rs = 0; rs < 16; ++rs) {
        size_t idx = (size_t)(r0 + rr * 16 + rs) * HH + h;
        float v = h2acc[idx] + U2[idx];
        h2acc[idx] = v;
        s += v;
        q = fmaf(v, v, q);
    }
    red[0][rr][h] = s;
    red[1][rr][h] = q;
    __syncthreads();
    if (t < 128) {
        atomicAdd(&stats[4 * HH + h], red[0][0][h] + red[0][1][h]);
        atomicAdd(&stats[5 * HH + h], red[1][0][h] + red[1][1][h]);
    }
}

// ---------------------------------------------------------------------------
// K5: finalize h1_out, h2_out = x_in + relu(bn(pre)).
// ---------------------------------------------------------------------------
__global__ __launch_bounds__(256) void k5_final(
    const float* __restrict__ h1_in, const float* __restrict__ h2_in,
    const float* __restrict__ h1p, const float* __restrict__ h2p,
    const float* __restrict__ g1, const float* __restrict__ be1,
    const float* __restrict__ g2, const float* __restrict__ be2,
    float* __restrict__ out,
    const float* __restrict__ stats)
{
    const float inv_n = 1.0f / 1024.0f;
    int idx0 = blockIdx.x * 2048 + threadIdx.x;
    #pragma unroll
    for (int p = 0; p < 8; ++p) {
        int idx = idx0 + p * 256;
        int region = idx >> 17;           // 0: h1, 1: h2
        int local = idx & 131071;
        int h = idx & 127;
        float ssum = stats[(2 + 2 * region) * HH + h];
        float ssq  = stats[(3 + 2 * region) * HH + h];
        float mean = ssum * inv_n;
        float var  = ssq * inv_n - mean * mean;
        float rstd = rsqrtf(var + EPS);
        const float* g  = region ? g2 : g1;
        const float* be = region ? be2 : be1;
        float sc = rstd * g[h];
        float sh = be[h] - mean * sc;
        const float* xin = region ? h2_in : h1_in;
        const float* pre = region ? h2p : h1p;
        out[idx] = xin[local] + fmaxf(fmaf(pre[local], sc, sh), 0.f);
    }
}

// ---------------------------------------------------------------------------
extern "C" void kernel_launch(void* const* d_in, const int* in_sizes, int n_in,
                              void* d_out, int out_size, void* d_ws, size_t ws_size,
                              hipStream_t stream) {
    const float* h1   = (const float*)d_in[0];
    const float* h2   = (const float*)d_in[1];
    const float* e    = (const float*)d_in[2];
    // d_in[3] = graph (unused for sum aggregation)
    const float* W_U1 = (const float*)d_in[4];
    const float* b_U1 = (const float*)d_in[5];
    const float* W_U2 = (const float*)d_in[6];
    const float* b_U2 = (const float*)d_in[7];
    const float* W_V1 = (const float*)d_in[8];
    const float* b_V1 = (const float*)d_in[9];
    const float* W_V2 = (const float*)d_in[10];
    const float* b_V2 = (const float*)d_in[11];
    const float* W_A1 = (const float*)d_in[12];
    const float* b_A1 = (const float*)d_in[13];
    const float* W_A2 = (const float*)d_in[14];
    const float* b_A2 = (const float*)d_in[15];
    const float* W_C  = (const float*)d_in[16];
    const float* b_C  = (const float*)d_in[17];
    const float* g_h1 = (const float*)d_in[18];
    const float* be_h1= (const float*)d_in[19];
    const float* g_h2 = (const float*)d_in[20];
    const float* be_h2= (const float*)d_in[21];
    const float* g_e  = (const float*)d_in[22];
    const float* be_e = (const float*)d_in[23];

    float* ws = (float*)d_ws;
    const size_t S = (size_t)BB * VV * HH;  // 131072
    float* U1  = ws + 0 * S;
    float* U2  = ws + 1 * S;
    float* V1  = ws + 2 * S;
    float* V2  = ws + 3 * S;
    float* V1f = ws + 4 * S;
    float* V2f = ws + 5 * S;
    float* A1f = ws + 6 * S;
    float* A2f = ws + 7 * S;
    float* h1acc = ws + 8 * S;
    float* h2acc = ws + 9 * S;
    float* stats = ws + 10 * S;              // 6*128 floats
    short* Whl  = (short*)(stats + 768);     // 64 KB
    unsigned short* e_newh = (unsigned short*)(Whl + 32768);

    const size_t EN = (size_t)BB * VV * VV * HH;   // 33.55M elements
    const size_t needed = (10 * S + 768) * 4 + 65536 + EN * 2;
    const bool useh = ws_size >= needed;

    float* out = (float*)d_out;
    float* eo = out + 2 * S;                 // e region

    // zero region: h1acc + h2acc + stats = 2*S + 768 floats (contiguous)
    const int nz4 = (int)((2 * S + 768) / 4);

    LinArgs la;
    la.x1 = h1; la.x2 = h2;
    la.W[0] = W_U1; la.b[0] = b_U1; la.b2[0] = nullptr; la.out[0] = U1; la.outf[0] = nullptr;
    la.W[1] = W_V1; la.b[1] = b_V1; la.b2[1] = nullptr; la.out[1] = V1; la.outf[1] = V1f;
    la.W[2] = W_A1; la.b[2] = b_A1; la.b2[2] = b_C;     la.out[2] = nullptr; la.outf[2] = A1f;
    la.W[3] = W_U2; la.b[3] = b_U2; la.b2[3] = nullptr; la.out[3] = U2; la.outf[3] = nullptr;
    la.W[4] = W_V2; la.b[4] = b_V2; la.b2[4] = nullptr; la.out[4] = V2; la.outf[4] = V2f;
    la.W[5] = W_A2; la.b[5] = b_A2; la.b2[5] = nullptr; la.out[5] = nullptr; la.outf[5] = A2f;
    k1_fused<<<144, 128, 0, stream>>>(la, W_C, Whl, (float4*)h1acc, nz4);

    if (useh) {
        k2_main<1><<<BB * VV * 2, 512, 0, stream>>>(e, Whl, A1f, A2f, V1f, V2f,
                                                    eo, e_newh, h1acc, stats);
        k4_pass2<1><<<1024 + 32, 256, 0, stream>>>(eo, e_newh, e, V1, V2,
                                                   g_e, be_e, h2acc,
                                                   h1acc, U1, stats);
    } else {
        k2_main<0><<<BB * VV * 2, 512, 0, stream>>>(e, Whl, A1f, A2f, V1f, V2f,
                                                    eo, e_newh, h1acc, stats);
        k4_pass2<0><<<1024 + 32, 256, 0, stream>>>(eo, e_newh, e, V1, V2,
                                                   g_e, be_e, h2acc,
                                                   h1acc, U1, stats);
    }

    k45_h2<<<32, 256, 0, stream>>>(h2acc, U2, stats);

    k5_final<<<128, 256, 0, stream>>>(h1, h2, h1acc, h2acc,
                                      g_h1, be_h1, g_h2, be_h2, out, stats);
}

// Round 13
// 177.913 us; speedup vs baseline: 1.0926x; 1.0519x over previous
//
#include <hip/hip_runtime.h>
#include <hip/hip_fp16.h>
#include <math.h>

#define BB 4
#define VV 256
#define HH 128
#define EPS 1e-5f

typedef __attribute__((ext_vector_type(8))) short short8;
typedef __attribute__((ext_vector_type(8))) __bf16 bf16x8;
typedef __attribute__((ext_vector_type(4))) float f32x4;

__device__ __forceinline__ float sigm_(float x) {
    float ex = __builtin_amdgcn_exp2f(-1.44269504f * x);
    return __builtin_amdgcn_rcpf(1.0f + ex);
}

__device__ __forceinline__ bf16x8 as_bf(short8 s) {
    union { short8 s; bf16x8 b; } u; u.s = s; return u.b;
}

// split via native converts (RNE); lo = RNE of residual
__device__ __forceinline__ void split8n(const float4 x0, const float4 x1,
                                        bf16x8& hi, bf16x8& lo) {
    float xs[8] = {x0.x, x0.y, x0.z, x0.w, x1.x, x1.y, x1.z, x1.w};
    #pragma unroll
    for (int i = 0; i < 8; ++i) {
        float x = xs[i];
        __bf16 h = (__bf16)x;
        float r = x - (float)h;
        hi[i] = h;
        lo[i] = (__bf16)r;
    }
}

// ---------------------------------------------------------------------------
// K1 fused: blocks 0-127: six linears (8 rows each). Blocks 128-143: W_C
// split into fragment-major bf16 hi/lo planes (PERMUTED: fragment ns, lane
// l15 holds W_C row n_phys = l15*8+ns). ALL blocks: grid-stride zero of
// h1acc/h2acc/stats.
// ---------------------------------------------------------------------------
struct LinArgs {
    const float* x1; const float* x2;
    const float* W[6]; const float* b[6]; const float* b2[6];
    float* out[6]; float* outf[6];
};

__global__ __launch_bounds__(128) void k1_fused(LinArgs a,
                                                const float* __restrict__ W_C,
                                                short* __restrict__ Whl,
                                                float4* __restrict__ zbase,
                                                int nz4) {
    const int blk = blockIdx.x;
    const int tid = threadIdx.x;
    // zero slice (all 144 blocks)
    {
        int gtid = blk * 128 + tid;
        float4 z = {0.f, 0.f, 0.f, 0.f};
        for (int i = gtid; i < nz4; i += 144 * 128) zbase[i] = z;
    }
    if (blk >= 128) {
        // W split: t in [0, 2048)
        int t = (blk - 128) * 128 + tid;
        int lane = t & 63;
        int grp = t >> 6;                     // kstep*8 + nsub
        int kstep = grp >> 3, nsub = grp & 7;
        int n = (lane & 15) * 8 + nsub;       // PERMUTED channel mapping
        int kb = kstep * 32 + ((lane >> 4) & 3) * 8;
        const float4* src = (const float4*)(W_C + (size_t)n * HH + kb);
        float4 x0 = src[0], x1 = src[1];
        bf16x8 hi, lo;
        split8n(x0, x1, hi, lo);
        union { bf16x8 b; short8 s; } uh, ul;
        uh.b = hi; ul.b = lo;
        short8* dst = (short8*)Whl;
        dst[(size_t)grp * 128 + 0 * 64 + lane] = uh.s;
        dst[(size_t)grp * 128 + 1 * 64 + lane] = ul.s;
        return;
    }
    // ---- six linears
    __shared__ float xs[2][8][HH];
    const int t = tid;
    const int r0 = blk * 8;
    {
        const float4* s1 = (const float4*)(a.x1 + (size_t)r0 * HH);
        const float4* s2 = (const float4*)(a.x2 + (size_t)r0 * HH);
        float4* d1 = (float4*)&xs[0][0][0];
        float4* d2 = (float4*)&xs[1][0][0];
        #pragma unroll
        for (int p = 0; p < 2; ++p) {
            d1[t + p * 128] = s1[t + p * 128];
            d2[t + p * 128] = s2[t + p * 128];
        }
    }
    __syncthreads();
    const int h = t;
    const int l15h = h >> 3, nsh = h & 7;     // PERMUTED fragment position
    for (int g = 0; g < 6; ++g) {
        const float* W = a.W[g];
        const float (*x)[HH] = (g < 3) ? xs[0] : xs[1];
        float acc[8];
        #pragma unroll
        for (int r = 0; r < 8; ++r) acc[r] = 0.f;
        const float4* Wrow = (const float4*)(W + (size_t)h * HH);
        #pragma unroll 8
        for (int kq = 0; kq < 32; ++kq) {
            float4 w4 = Wrow[kq];
            #pragma unroll
            for (int r = 0; r < 8; ++r) {
                float4 ev = *(const float4*)&x[r][kq * 4];
                acc[r] = fmaf(ev.x, w4.x, acc[r]);
                acc[r] = fmaf(ev.y, w4.y, acc[r]);
                acc[r] = fmaf(ev.z, w4.z, acc[r]);
                acc[r] = fmaf(ev.w, w4.w, acc[r]);
            }
        }
        float bias = a.b[g][h];
        if (a.b2[g]) bias += a.b2[g][h];
        if (a.out[g]) {
            float* O = a.out[g] + (size_t)r0 * HH + h;
            #pragma unroll
            for (int r = 0; r < 8; ++r) O[(size_t)r * HH] = acc[r] + bias;
        }
        if (a.outf[g]) {
            float* Of = a.outf[g];
            #pragma unroll
            for (int r = 0; r < 8; ++r)
                Of[((size_t)(r0 + r) * 16 + l15h) * 8 + nsh] = acc[r] + bias;
        }
    }
}

// ---------------------------------------------------------------------------
// K2 (r11 exact): per (b,i,jhalf): e_new = e@W_C^T + A1f + A2f; packed-fp16
// store; h1 partial agg (atomic) + e BN stats. 512 thr = 8 waves, wave w
// covers j in [jhalf*128 + w*16, +16), n full 128. acc = 32 AGPR. Full-K e
// preload (8 float4/lane) issued before W staging.
// ---------------------------------------------------------------------------
template<int STOREH>
__global__ __launch_bounds__(512, 4) void k2_main(
    const float* __restrict__ e,
    const short* __restrict__ Whl,
    const float* __restrict__ A1f, const float* __restrict__ A2f,
    const float* __restrict__ V1f, const float* __restrict__ V2f,
    float* __restrict__ e_new32,
    unsigned short* __restrict__ e_newh,
    float* __restrict__ h1acc,
    float* __restrict__ stats)
{
    __shared__ short8 sW[4096];          // 64 KB: full W hi/lo
    __shared__ float red[8][3][8][16];   // 12 KB [wave][qty][ns][l15]
    const int t = threadIdx.x;
    const int l = t & 63;
    const int w = t >> 6;
    const int l15 = l & 15;
    const int lq = (l >> 4) & 3;
    const int blk = blockIdx.x;
    const int bi = blk >> 1;             // b*V + i
    const int jhalf = blk & 1;
    const int b = bi >> 8;
    const int jbase = jhalf * 128 + w * 16;

    // ---- issue ALL e loads first (8 float4/lane, ride out HBM latency)
    const float* pa = e + (size_t)bi * (VV * HH) +
                      (size_t)(jbase + l15) * HH + lq * 8;
    float4 ec[8];
    #pragma unroll
    for (int kstep = 0; kstep < 4; ++kstep) {
        ec[2 * kstep]     = *(const float4*)(pa + kstep * 32);
        ec[2 * kstep + 1] = *(const float4*)(pa + kstep * 32 + 4);
    }

    // ---- stage W into LDS
    {
        const short8* src = (const short8*)Whl;
        #pragma unroll
        for (int p = 0; p < 8; ++p) sW[p * 512 + t] = src[p * 512 + t];
    }
    __syncthreads();

    f32x4 acc[8];
    #pragma unroll
    for (int ns = 0; ns < 8; ++ns) acc[ns] = (f32x4){0.f, 0.f, 0.f, 0.f};

    #pragma unroll
    for (int kstep = 0; kstep < 4; ++kstep) {
        bf16x8 ah, al;
        split8n(ec[2 * kstep], ec[2 * kstep + 1], ah, al);
        #pragma unroll
        for (int ns = 0; ns < 8; ++ns) {
            short8 bh = sW[(size_t)(kstep * 8 + ns) * 128 + l];
            short8 bl = sW[(size_t)(kstep * 8 + ns) * 128 + 64 + l];
            acc[ns] = __builtin_amdgcn_mfma_f32_16x16x32_bf16(
                ah, as_bf(bh), acc[ns], 0, 0, 0);
            acc[ns] = __builtin_amdgcn_mfma_f32_16x16x32_bf16(
                ah, as_bf(bl), acc[ns], 0, 0, 0);
            acc[ns] = __builtin_amdgcn_mfma_f32_16x16x32_bf16(
                al, as_bf(bh), acc[ns], 0, 0, 0);
        }
    }

    // ---- epilogue (fragment-major side loads; lane channel = l15*8+ns)
    union f8u { float4 v[2]; float f[8]; };
    f8u a2, v2;
    {
        const float4* p = (const float4*)(A2f + ((size_t)bi * 16 + l15) * 8);
        a2.v[0] = p[0]; a2.v[1] = p[1];
        const float4* q = (const float4*)(V2f + ((size_t)bi * 16 + l15) * 8);
        v2.v[0] = q[0]; v2.v[1] = q[1];
    }
    float h1a[8], es[8], eq[8];
    #pragma unroll
    for (int ns = 0; ns < 8; ++ns) { h1a[ns] = 0.f; es[ns] = 0.f; eq[ns] = 0.f; }

    #pragma unroll
    for (int r = 0; r < 4; ++r) {
        int j = jbase + lq * 4 + r;
        size_t fro = ((size_t)(b * VV + j) * 16 + l15) * 8;
        f8u a1, v1;
        {
            const float4* p = (const float4*)(A1f + fro);
            a1.v[0] = p[0]; a1.v[1] = p[1];
            const float4* q = (const float4*)(V1f + fro);
            v1.v[0] = q[0]; v1.v[1] = q[1];
        }
        size_t obase = ((size_t)bi * VV + j) * HH + l15 * 8;
        float en8[8];
        #pragma unroll
        for (int ns = 0; ns < 8; ++ns) {
            float en = acc[ns][r] + a1.f[ns] + a2.f[ns];
            en8[ns] = en;
            float s = sigm_(en);
            h1a[ns] = fmaf(s, v1.f[ns] + v2.f[ns], h1a[ns]);
            es[ns] += en;
            eq[ns] = fmaf(en, en, eq[ns]);
        }
        if (STOREH) {
            union { __half2 h[4]; uint4 u; } pk;
            pk.h[0] = __floats2half2_rn(en8[0], en8[1]);
            pk.h[1] = __floats2half2_rn(en8[2], en8[3]);
            pk.h[2] = __floats2half2_rn(en8[4], en8[5]);
            pk.h[3] = __floats2half2_rn(en8[6], en8[7]);
            *(uint4*)(e_newh + obase) = pk.u;
        } else {
            float4 s0 = {en8[0], en8[1], en8[2], en8[3]};
            float4 s1 = {en8[4], en8[5], en8[6], en8[7]};
            *(float4*)(e_new32 + obase) = s0;
            *(float4*)(e_new32 + obase + 4) = s1;
        }
    }

    #pragma unroll
    for (int ns = 0; ns < 8; ++ns) {
        h1a[ns] += __shfl_xor(h1a[ns], 16);
        h1a[ns] += __shfl_xor(h1a[ns], 32);
        es[ns]  += __shfl_xor(es[ns], 16);
        es[ns]  += __shfl_xor(es[ns], 32);
        eq[ns]  += __shfl_xor(eq[ns], 16);
        eq[ns]  += __shfl_xor(eq[ns], 32);
    }
    if (l < 16) {
        #pragma unroll
        for (int ns = 0; ns < 8; ++ns) {
            red[w][0][ns][l15] = h1a[ns];
            red[w][1][ns][l15] = es[ns];
            red[w][2][ns][l15] = eq[ns];
        }
    }
    __syncthreads();
    if (t < 128) {
        // thread t handles physical channel t = li*8 + ns
        int ns = t & 7, li = t >> 3;
        float h1t = 0.f, est = 0.f, eqt = 0.f;
        #pragma unroll
        for (int ww = 0; ww < 8; ++ww) {
            h1t += red[ww][0][ns][li];
            est += red[ww][1][ns][li];
            eqt += red[ww][2][ns][li];
        }
        atomicAdd(&h1acc[(size_t)bi * HH + t], h1t);
        atomicAdd(&stats[0 * HH + t], est);
        atomicAdd(&stats[1 * HH + t], eqt);
    }
}

// ---------------------------------------------------------------------------
// K4 (r9 exact): per (b, Jtile8, Iq8): stream I; h2 partials +
// BN(e)+relu+residual. READH: read fp16 e_new from ws, write f32 e_out.
// grid 1024 x 256. Thread owns (jsub=t>>5, 4 channels=(t&31)*4).
// ---------------------------------------------------------------------------
template<int READH>
__global__ __launch_bounds__(256) void k4_pass2(
    float* __restrict__ e_io,
    const unsigned short* __restrict__ e_newh,
    const float* __restrict__ e_in,
    const float* __restrict__ V1, const float* __restrict__ V2,
    const float* __restrict__ g_e, const float* __restrict__ be_e,
    float* __restrict__ h2acc,
    const float* __restrict__ stats)
{
    const int t = threadIdx.x;
    const int h4 = (t & 31) * 4;
    const int jsub = t >> 5;
    const int blk = blockIdx.x;       // ((b*32 + Jt)*8 + Iq)
    const int Iq = blk & 7;
    const int Jt = (blk >> 3) & 31;
    const int b = blk >> 8;
    const int J = Jt * 8 + jsub;
    const int bJ = (b << 8) + J;

    const float inv_n = 1.0f / (float)(BB * VV * VV);
    float sc[4], sh[4];
    #pragma unroll
    for (int c = 0; c < 4; ++c) {
        int h = h4 + c;
        float mean = stats[0 * HH + h] * inv_n;
        float var  = stats[1 * HH + h] * inv_n - mean * mean;
        float rstd = rsqrtf(var + EPS);
        sc[c] = rstd * g_e[h];
        sh[c] = be_e[h] - mean * sc[c];
    }
    float4 vh1 = *(const float4*)(V1 + (size_t)bJ * HH + h4);
    float4 h2a = {0.f, 0.f, 0.f, 0.f};

    const int I0beg = Iq * 32;
    for (int I0 = I0beg; I0 < I0beg + 32; I0 += 4) {
        float4 en[4], ei[4], v2[4];
        size_t off[4];
        #pragma unroll
        for (int u = 0; u < 4; ++u) {
            int I = I0 + u;
            off[u] = ((size_t)((b * VV + I) * VV) + J) * HH + h4;
            if (READH) {
                ushort4 eh = *(const ushort4*)(e_newh + off[u]);
                en[u].x = __half2float(__ushort_as_half(eh.x));
                en[u].y = __half2float(__ushort_as_half(eh.y));
                en[u].z = __half2float(__ushort_as_half(eh.z));
                en[u].w = __half2float(__ushort_as_half(eh.w));
            } else {
                en[u] = *(const float4*)(e_io + off[u]);
            }
            ei[u] = *(const float4*)(e_in + off[u]);
            v2[u] = *(const float4*)(V2 + (size_t)((b << 8) + I) * HH + h4);
        }
        #pragma unroll
        for (int u = 0; u < 4; ++u) {
            float4 r;
            float* enf = (float*)&en[u];
            float* eif = (float*)&ei[u];
            float* v2f = (float*)&v2[u];
            float* rf = (float*)&r;
            float* h2f = (float*)&h2a;
            float* v1f = (float*)&vh1;
            #pragma unroll
            for (int c = 0; c < 4; ++c) {
                float e_ = enf[c];
                h2f[c] = fmaf(sigm_(e_), v1f[c] + v2f[c], h2f[c]);
                float bn = fmaf(e_, sc[c], sh[c]);
                rf[c] = eif[c] + fmaxf(bn, 0.f);
            }
            *(float4*)(e_io + off[u]) = r;
        }
    }
    float* base = h2acc + (size_t)bJ * HH + h4;
    float* h2f = (float*)&h2a;
    #pragma unroll
    for (int c = 0; c < 4; ++c) atomicAdd(base + c, h2f[c]);
}

// ---------------------------------------------------------------------------
// K45: pre = U + acc; write back into acc (in place); h BN stats.
// grid 64 blocks x 256: region = blk>>5, 32 rows per block.
// ---------------------------------------------------------------------------
__global__ __launch_bounds__(256) void k45_combine(
    float* __restrict__ h1acc, float* __restrict__ h2acc,
    const float* __restrict__ U1, const float* __restrict__ U2,
    float* __restrict__ stats)
{
    __shared__ float red[2][2][128];
    const int t = threadIdx.x;
    const int h = t & 127;
    const int rr = t >> 7;
    const int region = blockIdx.x >> 5;
    const int r0 = (blockIdx.x & 31) * 32;
    float* acc = region ? h2acc : h1acc;
    const float* U = region ? U2 : U1;
    float s = 0.f, q = 0.f;
    #pragma unroll
    for (int rs = 0; rs < 16; ++rs) {
        size_t idx = (size_t)(r0 + rr * 16 + rs) * HH + h;
        float v = acc[idx] + U[idx];
        acc[idx] = v;
        s += v;
        q = fmaf(v, v, q);
    }
    red[0][rr][h] = s;
    red[1][rr][h] = q;
    __syncthreads();
    if (t < 128) {
        atomicAdd(&stats[(2 + 2 * region) * HH + h], red[0][0][h] + red[0][1][h]);
        atomicAdd(&stats[(3 + 2 * region) * HH + h], red[1][0][h] + red[1][1][h]);
    }
}

// ---------------------------------------------------------------------------
// K5: finalize h1_out, h2_out = x_in + relu(bn(pre)).
// ---------------------------------------------------------------------------
__global__ __launch_bounds__(256) void k5_final(
    const float* __restrict__ h1_in, const float* __restrict__ h2_in,
    const float* __restrict__ h1p, const float* __restrict__ h2p,
    const float* __restrict__ g1, const float* __restrict__ be1,
    const float* __restrict__ g2, const float* __restrict__ be2,
    float* __restrict__ out,
    const float* __restrict__ stats)
{
    const float inv_n = 1.0f / 1024.0f;
    int idx0 = blockIdx.x * 2048 + threadIdx.x;
    #pragma unroll
    for (int p = 0; p < 8; ++p) {
        int idx = idx0 + p * 256;
        int region = idx >> 17;           // 0: h1, 1: h2
        int local = idx & 131071;
        int h = idx & 127;
        float ssum = stats[(2 + 2 * region) * HH + h];
        float ssq  = stats[(3 + 2 * region) * HH + h];
        float mean = ssum * inv_n;
        float var  = ssq * inv_n - mean * mean;
        float rstd = rsqrtf(var + EPS);
        const float* g  = region ? g2 : g1;
        const float* be = region ? be2 : be1;
        float sc = rstd * g[h];
        float sh = be[h] - mean * sc;
        const float* xin = region ? h2_in : h1_in;
        const float* pre = region ? h2p : h1p;
        out[idx] = xin[local] + fmaxf(fmaf(pre[local], sc, sh), 0.f);
    }
}

// ---------------------------------------------------------------------------
extern "C" void kernel_launch(void* const* d_in, const int* in_sizes, int n_in,
                              void* d_out, int out_size, void* d_ws, size_t ws_size,
                              hipStream_t stream) {
    const float* h1   = (const float*)d_in[0];
    const float* h2   = (const float*)d_in[1];
    const float* e    = (const float*)d_in[2];
    // d_in[3] = graph (unused for sum aggregation)
    const float* W_U1 = (const float*)d_in[4];
    const float* b_U1 = (const float*)d_in[5];
    const float* W_U2 = (const float*)d_in[6];
    const float* b_U2 = (const float*)d_in[7];
    const float* W_V1 = (const float*)d_in[8];
    const float* b_V1 = (const float*)d_in[9];
    const float* W_V2 = (const float*)d_in[10];
    const float* b_V2 = (const float*)d_in[11];
    const float* W_A1 = (const float*)d_in[12];
    const float* b_A1 = (const float*)d_in[13];
    const float* W_A2 = (const float*)d_in[14];
    const float* b_A2 = (const float*)d_in[15];
    const float* W_C  = (const float*)d_in[16];
    const float* b_C  = (const float*)d_in[17];
    const float* g_h1 = (const float*)d_in[18];
    const float* be_h1= (const float*)d_in[19];
    const float* g_h2 = (const float*)d_in[20];
    const float* be_h2= (const float*)d_in[21];
    const float* g_e  = (const float*)d_in[22];
    const float* be_e = (const float*)d_in[23];

    float* ws = (float*)d_ws;
    const size_t S = (size_t)BB * VV * HH;  // 131072
    float* U1  = ws + 0 * S;
    float* U2  = ws + 1 * S;
    float* V1  = ws + 2 * S;
    float* V2  = ws + 3 * S;
    float* V1f = ws + 4 * S;
    float* V2f = ws + 5 * S;
    float* A1f = ws + 6 * S;
    float* A2f = ws + 7 * S;
    float* h1acc = ws + 8 * S;
    float* h2acc = ws + 9 * S;
    float* stats = ws + 10 * S;              // 6*128 floats
    short* Whl  = (short*)(stats + 768);     // 64 KB
    unsigned short* e_newh = (unsigned short*)(Whl + 32768);

    const size_t EN = (size_t)BB * VV * VV * HH;   // 33.55M elements
    const size_t needed = (10 * S + 768) * 4 + 65536 + EN * 2;
    const bool useh = ws_size >= needed;

    float* out = (float*)d_out;
    float* eo = out + 2 * S;                 // e region

    // zero region: h1acc + h2acc + stats = 2*S + 768 floats (contiguous)
    const int nz4 = (int)((2 * S + 768) / 4);

    LinArgs la;
    la.x1 = h1; la.x2 = h2;
    la.W[0] = W_U1; la.b[0] = b_U1; la.b2[0] = nullptr; la.out[0] = U1; la.outf[0] = nullptr;
    la.W[1] = W_V1; la.b[1] = b_V1; la.b2[1] = nullptr; la.out[1] = V1; la.outf[1] = V1f;
    la.W[2] = W_A1; la.b[2] = b_A1; la.b2[2] = b_C;     la.out[2] = nullptr; la.outf[2] = A1f;
    la.W[3] = W_U2; la.b[3] = b_U2; la.b2[3] = nullptr; la.out[3] = U2; la.outf[3] = nullptr;
    la.W[4] = W_V2; la.b[4] = b_V2; la.b2[4] = nullptr; la.out[4] = V2; la.outf[4] = V2f;
    la.W[5] = W_A2; la.b[5] = b_A2; la.b2[5] = nullptr; la.out[5] = nullptr; la.outf[5] = A2f;
    k1_fused<<<144, 128, 0, stream>>>(la, W_C, Whl, (float4*)h1acc, nz4);

    if (useh) {
        k2_main<1><<<BB * VV * 2, 512, 0, stream>>>(e, Whl, A1f, A2f, V1f, V2f,
                                                    eo, e_newh, h1acc, stats);
        k4_pass2<1><<<BB * 32 * 8, 256, 0, stream>>>(eo, e_newh, e, V1, V2,
                                                     g_e, be_e, h2acc, stats);
    } else {
        k2_main<0><<<BB * VV * 2, 512, 0, stream>>>(e, Whl, A1f, A2f, V1f, V2f,
                                                    eo, e_newh, h1acc, stats);
        k4_pass2<0><<<BB * 32 * 8, 256, 0, stream>>>(eo, e_newh, e, V1, V2,
                                                     g_e, be_e, h2acc, stats);
    }

    k45_combine<<<64, 256, 0, stream>>>(h1acc, h2acc, U1, U2, stats);

    k5_final<<<128, 256, 0, stream>>>(h1, h2, h1acc, h2acc,
                                      g_h1, be_h1, g_h2, be_h2, out, stats);
}